// Round 11
// baseline (33.026 us; speedup 1.0000x reference)
//
#include <hip/hip_runtime.h>

#define NPERS 64
#define NJOINT 15
#define NDEPTH 128
#define BIGF 100000.0f
#define EPSF 1e-8f
#define QS 4                 // q-split: 4 waves, 16 candidates each
#define QCHUNK (NPERS / QS)

// element e (0..3) of float4 v, compile-time e
#define F4E(v, e) ((e) == 0 ? (v).x : (e) == 1 ? (v).y : (e) == 2 ? (v).z : (v).w)

// R10 + register-budget fix: amdgpu_waves_per_eu(2,2) pins 2 waves/SIMD
// (matching the grid: 512 blocks = 2 blocks/CU = 8 waves/CU) so the
// allocator gets the 256-VGPR budget and the X/Y tile stops spilling.
// Coef loads are j-chunked (12 live regs instead of 48) to cut peak pressure.
__global__ __launch_bounds__(256)
__attribute__((amdgpu_waves_per_eu(2, 2)))
void pose_match_kernel(
    const float* __restrict__ poses_3d,   // (B,NP,NJ,ND,3)
    const float* __restrict__ p2d,        // (B,NP,NJ,2)
    const float* __restrict__ vis,        // (B,NP,NJ)
    const int*   __restrict__ nper,       // (B,)
    const float* __restrict__ Rm,         // (B,3,3)
    const float* __restrict__ Tm,         // (B,3)
    const float* __restrict__ fm,         // (B,2)
    const float* __restrict__ cm,         // (B,2)
    const float* __restrict__ iw_,        // (B,)
    const float* __restrict__ ih_,        // (B,)
    float* __restrict__ out)              // (B,NP,NJ,ND)
{
    const int b    = blockIdx.x >> 5;     // 32 person-pairs per batch
    const int pp   = blockIdx.x & 31;
    const int p0   = pp * 2;
    const int tid  = threadIdx.x;
    const int wv   = tid >> 6;            // wave id 0..3 == q-slice
    const int lane = tid & 63;            // d = lane + dh*64

    __shared__ float4 sq[NPERS][NJOINT];  // {vis, rx, ry, _}  (phase 2)
    __shared__ float4 sco[NPERS][12];     // w[15],c | wx[15],0 | wy[15],0
    __shared__ float  bvred[QS][4][64];   // [slice][combo][lane]
    __shared__ int    bqred[QS][4][64];

    // ---- stage raw candidate data ----
    for (int i = tid; i < NPERS * NJOINT; i += 256) {
        int q = i / NJOINT, j = i % NJOINT;
        float v  = vis[(b * NPERS + q) * NJOINT + j];
        float rx = p2d[((b * NPERS + q) * NJOINT + j) * 2 + 0];
        float ry = p2d[((b * NPERS + q) * NJOINT + j) * 2 + 1];
        sq[q][j] = make_float4(v, rx, ry, 0.0f);
    }
    __syncthreads();

    // ---- fold into matching coefficients (threads 0..63, one q each) ----
    if (tid < NPERS) {
        const int q = tid;
        float vs = 0.0f, t2 = 0.0f;
        #pragma unroll
        for (int j = 0; j < NJOINT; ++j) {
            float4 s = sq[q][j];
            vs += s.x;
            t2 = fmaf(s.y * s.y + s.z * s.z, s.x, t2);
        }
        float inv = 1.0f / (vs + EPSF);
        float* o = (float*)&sco[q][0];
        #pragma unroll
        for (int j = 0; j < NJOINT; ++j) {
            float4 s = sq[q][j];
            o[j]      = s.x * inv;
            o[16 + j] = 2.0f * s.x * s.y * inv;
            o[32 + j] = 2.0f * s.x * s.z * inv;
        }
        o[15] = t2 * inv;      // c term
        o[31] = 0.0f;
        o[47] = 0.0f;
    }
    __syncthreads();

    // ---- camera params (wave-uniform) ----
    const float R00 = Rm[b*9+0], R01 = Rm[b*9+1], R02 = Rm[b*9+2];
    const float R10 = Rm[b*9+3], R11 = Rm[b*9+4], R12 = Rm[b*9+5];
    const float R20 = Rm[b*9+6], R21 = Rm[b*9+7], R22 = Rm[b*9+8];
    const float T0 = Tm[b*3+0], T1 = Tm[b*3+1], T2 = Tm[b*3+2];
    const float fx = fm[b*2+0], fy = fm[b*2+1];
    const float cx = cm[b*2+0], cy = cm[b*2+1];
    const float iwm1 = iw_[b] - 1.0f;
    const float ihm1 = ih_[b] - 1.0f;
    const int   npv  = nper[b];

    // ---- project 15 joints for the 2x2 (person, depth-half) tile ----
    float X[2][2][NJOINT], Y[2][2][NJOINT];
    #pragma unroll
    for (int pi = 0; pi < 2; ++pi) {
        #pragma unroll
        for (int dh = 0; dh < 2; ++dh) {
            const int d = lane + dh * 64;
            #pragma unroll
            for (int j = 0; j < NJOINT; ++j) {
                int base = (((b * NPERS + p0 + pi) * NJOINT + j) * NDEPTH + d) * 3;
                float a0 = poses_3d[base + 0] - T0;
                float a1 = poses_3d[base + 1] - T1;
                float a2 = poses_3d[base + 2] - T2;
                float xc0 = R00 * a0 + R01 * a1 + R02 * a2;
                float xc1 = R10 * a0 + R11 * a1 + R12 * a2;
                float xc2 = R20 * a0 + R21 * a1 + R22 * a2;
                float r   = __builtin_amdgcn_rcpf(xc2);
                X[pi][dh][j] = fmaf(fx * xc0, r, cx);
                Y[pi][dh][j] = fmaf(fy * xc1, r, cy);
            }
        }
    }

    // ---- partial argmin: this wave's 16-candidate slice, 4 combos ----
    float bv00 = 3.0e38f, bv01 = 3.0e38f, bv10 = 3.0e38f, bv11 = 3.0e38f;
    int   bq00 = 0, bq01 = 0, bq10 = 0, bq11 = 0;
    const int q0 = wv * QCHUNK;
    #pragma unroll 1
    for (int q = q0; q < q0 + QCHUNK; ++q) {
        const float c = sco[q][3].w;
        float a00 = c, a01 = c, a10 = c, a11 = c;
        // j-chunked: only 3 float4 of coefficients live at a time
        #pragma unroll
        for (int k = 0; k < 4; ++k) {
            float4 cw4 = sco[q][k];
            float4 cx4 = sco[q][4 + k];
            float4 cy4 = sco[q][8 + k];
            #pragma unroll
            for (int e = 0; e < 4; ++e) {
                if (k == 3 && e == 3) continue;   // j = 15 doesn't exist
                float w  = F4E(cw4, e);
                float wx = F4E(cx4, e);
                float wy = F4E(cy4, e);
                const int j = k * 4 + e;
                float u;
                u = fmaf(w, X[0][0][j], -wx); a00 = fmaf(X[0][0][j], u, a00);
                u = fmaf(w, Y[0][0][j], -wy); a00 = fmaf(Y[0][0][j], u, a00);
                u = fmaf(w, X[0][1][j], -wx); a01 = fmaf(X[0][1][j], u, a01);
                u = fmaf(w, Y[0][1][j], -wy); a01 = fmaf(Y[0][1][j], u, a01);
                u = fmaf(w, X[1][0][j], -wx); a10 = fmaf(X[1][0][j], u, a10);
                u = fmaf(w, Y[1][0][j], -wy); a10 = fmaf(Y[1][0][j], u, a10);
                u = fmaf(w, X[1][1][j], -wx); a11 = fmaf(X[1][1][j], u, a11);
                u = fmaf(w, Y[1][1][j], -wy); a11 = fmaf(Y[1][1][j], u, a11);
            }
        }
        if (q >= npv) { a00 = BIGF; a01 = BIGF; a10 = BIGF; a11 = BIGF; }
        if (a00 < bv00) { bv00 = a00; bq00 = q; }   // ascending q, strict <
        if (a01 < bv01) { bv01 = a01; bq01 = q; }
        if (a10 < bv10) { bv10 = a10; bq10 = q; }
        if (a11 < bv11) { bv11 = a11; bq11 = q; }
    }
    // combo index: pi*2 + dh
    bvred[wv][0][lane] = bv00;  bqred[wv][0][lane] = bq00;
    bvred[wv][1][lane] = bv01;  bqred[wv][1][lane] = bq01;
    bvred[wv][2][lane] = bv10;  bqred[wv][2][lane] = bq10;
    bvred[wv][3][lane] = bv11;  bqred[wv][3][lane] = bq11;
    __syncthreads();

    // ---- each wave finishes ONE combo; static unroll + uniform branch so
    //      X/Y indices stay compile-time (no scratch, rule #20) ----
    #pragma unroll
    for (int pi = 0; pi < 2; ++pi) {
        #pragma unroll
        for (int dh = 0; dh < 2; ++dh) {
            const int combo = pi * 2 + dh;
            if (wv == combo) {              // wave-uniform -> s_cbranch skip
                float bestv = 3.0e38f;
                int   bestq = 0;
                #pragma unroll
                for (int k = 0; k < QS; ++k) {   // ascending slice == asc. q
                    float v = bvred[k][combo][lane];
                    if (v < bestv) { bestv = v; bestq = bqred[k][combo][lane]; }
                }
                const int d = lane + dh * 64;
                const int obase = ((b * NPERS + p0 + pi) * NJOINT) * NDEPTH + d;
                #pragma unroll
                for (int j = 0; j < NJOINT; ++j) {
                    float4 v = sq[bestq][j];
                    float xx = X[pi][dh][j], yy = Y[pi][dh][j];
                    float dx = xx - v.y;
                    float dy = yy - v.z;
                    float md = fmaf(dx, dx, dy * dy);
                    float sc = __expf(-md * (1.0f / 225.0f));
                    float inb = (xx >= 0.0f && yy >= 0.0f &&
                                 xx <= iwm1 && yy <= ihm1) ? 1.0f : 0.0f;
                    out[obase + j * NDEPTH] = sc * inb * v.x;
                }
            }
        }
    }
}

extern "C" void kernel_launch(void* const* d_in, const int* in_sizes, int n_in,
                              void* d_out, int out_size, void* d_ws, size_t ws_size,
                              hipStream_t stream) {
    const float* poses_3d = (const float*)d_in[0];
    const float* p2d      = (const float*)d_in[1];
    const float* vis      = (const float*)d_in[2];
    const int*   nper     = (const int*)d_in[3];
    const float* Rm       = (const float*)d_in[4];
    const float* Tm       = (const float*)d_in[5];
    const float* fm       = (const float*)d_in[6];
    const float* cm       = (const float*)d_in[7];
    const float* iw       = (const float*)d_in[8];
    const float* ih       = (const float*)d_in[9];
    float* out = (float*)d_out;

    const int B = in_sizes[3];  // num_persons_ref has B elements
    dim3 grid(B * 32);          // (b, person-pair)
    dim3 block(256);            // 4 waves: q-slice x combo
    pose_match_kernel<<<grid, block, 0, stream>>>(
        poses_3d, p2d, vis, nper, Rm, Tm, fm, cm, iw, ih, out);
}

// Round 12
// 29.163 us; speedup vs baseline: 1.1325x; 1.1325x over previous
//
#include <hip/hip_runtime.h>

#define NPERS 64
#define NJOINT 15
#define NDEPTH 128
#define BIGF 100000.0f
#define EPSF 1e-8f
#define INFF 3.0e38f

// element e (0..3) of float4 v, compile-time e
#define F4E(v, e) ((e) == 0 ? (v).x : (e) == 1 ? (v).y : (e) == 2 ? (v).z : (v).w)

// Designed for a 128-VGPR budget (R10/R11 lesson: the allocator won't give
// more): tile = 2 persons x 1 depth (X/Y = 60 regs, live ~105), 4 waves/SIMD.
// npv-skip: invalid candidates (q >= npv) are never computed; argmin is
// initialized to (BIG, npv) [npv<64] or (+inf, 0) [npv=64], which reproduces
// np.argmin over the BIG-clamped array exactly. Waves take strided q slices;
// the cross-wave combine orders by (value, q) so ties resolve to smallest q.
__global__ __launch_bounds__(256, 4)
void pose_match_kernel(
    const float* __restrict__ poses_3d,   // (B,NP,NJ,ND,3)
    const float* __restrict__ p2d,        // (B,NP,NJ,2)
    const float* __restrict__ vis,        // (B,NP,NJ)
    const int*   __restrict__ nper,       // (B,)
    const float* __restrict__ Rm,         // (B,3,3)
    const float* __restrict__ Tm,         // (B,3)
    const float* __restrict__ fm,         // (B,2)
    const float* __restrict__ cm,         // (B,2)
    const float* __restrict__ iw_,        // (B,)
    const float* __restrict__ ih_,        // (B,)
    float* __restrict__ out)              // (B,NP,NJ,ND)
{
    const int b    = blockIdx.x >> 6;     // 64 blocks per batch: 32 pp x 2 dh
    const int rem  = blockIdx.x & 63;
    const int pp   = rem >> 1;
    const int dh   = rem & 1;
    const int p0   = pp * 2;
    const int tid  = threadIdx.x;
    const int wv   = tid >> 6;            // wave id 0..3 = strided q-slice
    const int lane = tid & 63;
    const int d    = dh * 64 + lane;      // this thread's depth bin

    __shared__ float4 sq[NPERS][NJOINT];  // {vis, rx, ry, _}  (phase 2)
    __shared__ float4 sco[NPERS][12];     // w[15],c | wx[15],0 | wy[15],0
    __shared__ float  bvred[4][2][64];    // [wave][person][lane]
    __shared__ int    bqred[4][2][64];

    // ---- stage raw candidate data ----
    for (int i = tid; i < NPERS * NJOINT; i += 256) {
        int q = i / NJOINT, j = i % NJOINT;
        float v  = vis[(b * NPERS + q) * NJOINT + j];
        float rx = p2d[((b * NPERS + q) * NJOINT + j) * 2 + 0];
        float ry = p2d[((b * NPERS + q) * NJOINT + j) * 2 + 1];
        sq[q][j] = make_float4(v, rx, ry, 0.0f);
    }
    __syncthreads();

    // ---- fold into matching coefficients (threads 0..63, one q each) ----
    if (tid < NPERS) {
        const int q = tid;
        float vs = 0.0f, t2 = 0.0f;
        #pragma unroll
        for (int j = 0; j < NJOINT; ++j) {
            float4 s = sq[q][j];
            vs += s.x;
            t2 = fmaf(s.y * s.y + s.z * s.z, s.x, t2);
        }
        float inv = 1.0f / (vs + EPSF);
        float* o = (float*)&sco[q][0];
        #pragma unroll
        for (int j = 0; j < NJOINT; ++j) {
            float4 s = sq[q][j];
            o[j]      = s.x * inv;
            o[16 + j] = 2.0f * s.x * s.y * inv;
            o[32 + j] = 2.0f * s.x * s.z * inv;
        }
        o[15] = t2 * inv;      // c term
        o[31] = 0.0f;
        o[47] = 0.0f;
    }
    __syncthreads();

    // ---- camera params (wave-uniform) ----
    const float R00 = Rm[b*9+0], R01 = Rm[b*9+1], R02 = Rm[b*9+2];
    const float R10 = Rm[b*9+3], R11 = Rm[b*9+4], R12 = Rm[b*9+5];
    const float R20 = Rm[b*9+6], R21 = Rm[b*9+7], R22 = Rm[b*9+8];
    const float T0 = Tm[b*3+0], T1 = Tm[b*3+1], T2 = Tm[b*3+2];
    const float fx = fm[b*2+0], fy = fm[b*2+1];
    const float cx = cm[b*2+0], cy = cm[b*2+1];
    const float iwm1 = iw_[b] - 1.0f;
    const float ihm1 = ih_[b] - 1.0f;
    const int   npv  = nper[b];

    // ---- project 15 joints for the 2 persons at depth d (separate named
    //      arrays: every index compile-time, rule #20) ----
    float X0[NJOINT], Y0[NJOINT], X1[NJOINT], Y1[NJOINT];
    #pragma unroll
    for (int j = 0; j < NJOINT; ++j) {
        int base = (((b * NPERS + p0) * NJOINT + j) * NDEPTH + d) * 3;
        float a0 = poses_3d[base + 0] - T0;
        float a1 = poses_3d[base + 1] - T1;
        float a2 = poses_3d[base + 2] - T2;
        float xc0 = R00 * a0 + R01 * a1 + R02 * a2;
        float xc1 = R10 * a0 + R11 * a1 + R12 * a2;
        float xc2 = R20 * a0 + R21 * a1 + R22 * a2;
        float r   = __builtin_amdgcn_rcpf(xc2);
        X0[j] = fmaf(fx * xc0, r, cx);
        Y0[j] = fmaf(fy * xc1, r, cy);
    }
    #pragma unroll
    for (int j = 0; j < NJOINT; ++j) {
        int base = (((b * NPERS + p0 + 1) * NJOINT + j) * NDEPTH + d) * 3;
        float a0 = poses_3d[base + 0] - T0;
        float a1 = poses_3d[base + 1] - T1;
        float a2 = poses_3d[base + 2] - T2;
        float xc0 = R00 * a0 + R01 * a1 + R02 * a2;
        float xc1 = R10 * a0 + R11 * a1 + R12 * a2;
        float xc2 = R20 * a0 + R21 * a1 + R22 * a2;
        float r   = __builtin_amdgcn_rcpf(xc2);
        X1[j] = fmaf(fx * xc0, r, cx);
        Y1[j] = fmaf(fy * xc1, r, cy);
    }

    // ---- argmin init == np.argmin over BIG-clamped array ----
    float bv0, bv1;
    int   bq0, bq1;
    if (npv < NPERS) { bv0 = bv1 = BIGF; bq0 = bq1 = npv; }
    else             { bv0 = bv1 = INFF; bq0 = bq1 = 0;   }

    // ---- strided q-loop over VALID candidates only ----
    for (int q = wv; q < npv; q += 4) {
        const float c = sco[q][3].w;
        float a0 = c, a1 = c;
        #pragma unroll
        for (int k = 0; k < 4; ++k) {
            float4 cw4 = sco[q][k];
            float4 cx4 = sco[q][4 + k];
            float4 cy4 = sco[q][8 + k];
            #pragma unroll
            for (int e = 0; e < 4; ++e) {
                if (k == 3 && e == 3) continue;   // j = 15 doesn't exist
                const int j = k * 4 + e;
                float w  = F4E(cw4, e);
                float wx = F4E(cx4, e);
                float wy = F4E(cy4, e);
                float u;
                u = fmaf(w, X0[j], -wx); a0 = fmaf(X0[j], u, a0);
                u = fmaf(w, Y0[j], -wy); a0 = fmaf(Y0[j], u, a0);
                u = fmaf(w, X1[j], -wx); a1 = fmaf(X1[j], u, a1);
                u = fmaf(w, Y1[j], -wy); a1 = fmaf(Y1[j], u, a1);
            }
        }
        // ascending within wave -> strict < keeps earliest q
        if (a0 < bv0) { bv0 = a0; bq0 = q; }
        if (a1 < bv1) { bv1 = a1; bq1 = q; }
    }
    bvred[wv][0][lane] = bv0;  bqred[wv][0][lane] = bq0;
    bvred[wv][1][lane] = bv1;  bqred[wv][1][lane] = bq1;
    __syncthreads();

    // ---- waves 0,1 finish person 0,1: combine by (value, q) + epilogue ----
#define EPILOGUE(PI, XA, YA)                                                  \
    if (wv == PI) {                                                           \
        float bestv = bvred[0][PI][lane];                                     \
        int   bestq = bqred[0][PI][lane];                                     \
        _Pragma("unroll")                                                     \
        for (int k = 1; k < 4; ++k) {                                         \
            float v  = bvred[k][PI][lane];                                    \
            int   qq = bqred[k][PI][lane];                                    \
            if (v < bestv || (v == bestv && qq < bestq)) {                    \
                bestv = v; bestq = qq;                                        \
            }                                                                 \
        }                                                                     \
        const int obase = ((b * NPERS + p0 + PI) * NJOINT) * NDEPTH + d;      \
        _Pragma("unroll")                                                     \
        for (int j = 0; j < NJOINT; ++j) {                                    \
            float4 v = sq[bestq][j];                                          \
            float xx = XA[j], yy = YA[j];                                     \
            float dx = xx - v.y;                                              \
            float dy = yy - v.z;                                              \
            float md = fmaf(dx, dx, dy * dy);                                 \
            float sc = __expf(-md * (1.0f / 225.0f));                         \
            float inb = (xx >= 0.0f && yy >= 0.0f &&                          \
                         xx <= iwm1 && yy <= ihm1) ? 1.0f : 0.0f;             \
            out[obase + j * NDEPTH] = sc * inb * v.x;                         \
        }                                                                     \
    }

    EPILOGUE(0, X0, Y0)
    EPILOGUE(1, X1, Y1)
#undef EPILOGUE
}

extern "C" void kernel_launch(void* const* d_in, const int* in_sizes, int n_in,
                              void* d_out, int out_size, void* d_ws, size_t ws_size,
                              hipStream_t stream) {
    const float* poses_3d = (const float*)d_in[0];
    const float* p2d      = (const float*)d_in[1];
    const float* vis      = (const float*)d_in[2];
    const int*   nper     = (const int*)d_in[3];
    const float* Rm       = (const float*)d_in[4];
    const float* Tm       = (const float*)d_in[5];
    const float* fm       = (const float*)d_in[6];
    const float* cm       = (const float*)d_in[7];
    const float* iw       = (const float*)d_in[8];
    const float* ih       = (const float*)d_in[9];
    float* out = (float*)d_out;

    const int B = in_sizes[3];  // num_persons_ref has B elements
    dim3 grid(B * 64);          // (b, person-pair, depth-half)
    dim3 block(256);            // 4 waves = 4 strided q-slices
    pose_match_kernel<<<grid, block, 0, stream>>>(
        poses_3d, p2d, vis, nper, Rm, Tm, fm, cm, iw, ih, out);
}

// Round 13
// 26.964 us; speedup vs baseline: 1.2248x; 1.0815x over previous
//
#include <hip/hip_runtime.h>

#define NPERS 64
#define NJOINT 15
#define NDEPTH 128
#define BIGF 100000.0f
#define EPSF 1e-8f
#define INFF 3.0e38f

// element e (0..3) of float4 v, compile-time e
#define F4E(v, e) ((e) == 0 ? (v).x : (e) == 1 ? (v).y : (e) == 2 ? (v).z : (v).w)

// R12 + allocator fix: NO __launch_bounds__ (it installs its own waves-per-eu
// range and overrides the attribute — R11 evidence); instead
// amdgpu_waves_per_eu(2,2) pins occupancy at exactly 2 waves/EU so the
// allocator has a 256-VGPR budget and zero incentive to spill the 60-float
// X/Y tile (R9-R12 all spilled at 64-128 VGPR).
// Also: coefficient fold now builds rows in registers and stores 12
// ds_write_b128 into a [13]-padded row (was 45 scalar stores at 16-way
// bank conflict -> 680K SQ_LDS_BANK_CONFLICT in R12).
__global__
__attribute__((amdgpu_flat_work_group_size(256, 256)))
__attribute__((amdgpu_waves_per_eu(2, 2)))
void pose_match_kernel(
    const float* __restrict__ poses_3d,   // (B,NP,NJ,ND,3)
    const float* __restrict__ p2d,        // (B,NP,NJ,2)
    const float* __restrict__ vis,        // (B,NP,NJ)
    const int*   __restrict__ nper,       // (B,)
    const float* __restrict__ Rm,         // (B,3,3)
    const float* __restrict__ Tm,         // (B,3)
    const float* __restrict__ fm,         // (B,2)
    const float* __restrict__ cm,         // (B,2)
    const float* __restrict__ iw_,        // (B,)
    const float* __restrict__ ih_,        // (B,)
    float* __restrict__ out)              // (B,NP,NJ,ND)
{
    const int b    = blockIdx.x >> 6;     // 64 blocks per batch: 32 pp x 2 dh
    const int rem  = blockIdx.x & 63;
    const int pp   = rem >> 1;
    const int dh   = rem & 1;
    const int p0   = pp * 2;
    const int tid  = threadIdx.x;
    const int wv   = tid >> 6;            // wave id 0..3 = strided q-slice
    const int lane = tid & 63;
    const int d    = dh * 64 + lane;      // this thread's depth bin

    __shared__ float4 sq[NPERS][NJOINT];  // {vis, rx, ry, _}  (phase 2)
    __shared__ float4 sco[NPERS][13];     // w[15],c | wx[15],0 | wy[15],0 | pad
    __shared__ float  bvred[4][2][64];    // [wave][person][lane]
    __shared__ int    bqred[4][2][64];

    // ---- stage raw candidate data ----
    for (int i = tid; i < NPERS * NJOINT; i += 256) {
        int q = i / NJOINT, j = i % NJOINT;
        float v  = vis[(b * NPERS + q) * NJOINT + j];
        float rx = p2d[((b * NPERS + q) * NJOINT + j) * 2 + 0];
        float ry = p2d[((b * NPERS + q) * NJOINT + j) * 2 + 1];
        sq[q][j] = make_float4(v, rx, ry, 0.0f);
    }
    __syncthreads();

    // ---- fold coefficients in REGISTERS, store as 12 ds_write_b128 ----
    if (tid < NPERS) {
        const int q = tid;
        float vs = 0.0f, t2 = 0.0f;
        #pragma unroll
        for (int j = 0; j < NJOINT; ++j) {
            float4 s = sq[q][j];
            vs += s.x;
            t2 = fmaf(s.y * s.y + s.z * s.z, s.x, t2);
        }
        float inv = 1.0f / (vs + EPSF);
        float o[48];                       // compile-time indexed only
        #pragma unroll
        for (int j = 0; j < NJOINT; ++j) {
            float4 s = sq[q][j];
            o[j]      = s.x * inv;
            o[16 + j] = 2.0f * s.x * s.y * inv;
            o[32 + j] = 2.0f * s.x * s.z * inv;
        }
        o[15] = t2 * inv;      // c term
        o[31] = 0.0f;
        o[47] = 0.0f;
        #pragma unroll
        for (int k = 0; k < 12; ++k)
            sco[q][k] = make_float4(o[4*k], o[4*k+1], o[4*k+2], o[4*k+3]);
    }
    __syncthreads();

    // ---- camera params (wave-uniform) ----
    const float R00 = Rm[b*9+0], R01 = Rm[b*9+1], R02 = Rm[b*9+2];
    const float R10 = Rm[b*9+3], R11 = Rm[b*9+4], R12 = Rm[b*9+5];
    const float R20 = Rm[b*9+6], R21 = Rm[b*9+7], R22 = Rm[b*9+8];
    const float T0 = Tm[b*3+0], T1 = Tm[b*3+1], T2 = Tm[b*3+2];
    const float fx = fm[b*2+0], fy = fm[b*2+1];
    const float cx = cm[b*2+0], cy = cm[b*2+1];
    const float iwm1 = iw_[b] - 1.0f;
    const float ihm1 = ih_[b] - 1.0f;
    const int   npv  = nper[b];

    // ---- project 15 joints for the 2 persons at depth d ----
    float X0[NJOINT], Y0[NJOINT], X1[NJOINT], Y1[NJOINT];
    #pragma unroll
    for (int j = 0; j < NJOINT; ++j) {
        int base = (((b * NPERS + p0) * NJOINT + j) * NDEPTH + d) * 3;
        float a0 = poses_3d[base + 0] - T0;
        float a1 = poses_3d[base + 1] - T1;
        float a2 = poses_3d[base + 2] - T2;
        float xc0 = R00 * a0 + R01 * a1 + R02 * a2;
        float xc1 = R10 * a0 + R11 * a1 + R12 * a2;
        float xc2 = R20 * a0 + R21 * a1 + R22 * a2;
        float r   = __builtin_amdgcn_rcpf(xc2);
        X0[j] = fmaf(fx * xc0, r, cx);
        Y0[j] = fmaf(fy * xc1, r, cy);
    }
    #pragma unroll
    for (int j = 0; j < NJOINT; ++j) {
        int base = (((b * NPERS + p0 + 1) * NJOINT + j) * NDEPTH + d) * 3;
        float a0 = poses_3d[base + 0] - T0;
        float a1 = poses_3d[base + 1] - T1;
        float a2 = poses_3d[base + 2] - T2;
        float xc0 = R00 * a0 + R01 * a1 + R02 * a2;
        float xc1 = R10 * a0 + R11 * a1 + R12 * a2;
        float xc2 = R20 * a0 + R21 * a1 + R22 * a2;
        float r   = __builtin_amdgcn_rcpf(xc2);
        X1[j] = fmaf(fx * xc0, r, cx);
        Y1[j] = fmaf(fy * xc1, r, cy);
    }

    // ---- argmin init == np.argmin over BIG-clamped array ----
    float bv0, bv1;
    int   bq0, bq1;
    if (npv < NPERS) { bv0 = bv1 = BIGF; bq0 = bq1 = npv; }
    else             { bv0 = bv1 = INFF; bq0 = bq1 = 0;   }

    // ---- strided q-loop over VALID candidates only ----
    for (int q = wv; q < npv; q += 4) {
        const float c = sco[q][3].w;
        float a0 = c, a1 = c;
        #pragma unroll
        for (int k = 0; k < 4; ++k) {
            float4 cw4 = sco[q][k];
            float4 cx4 = sco[q][4 + k];
            float4 cy4 = sco[q][8 + k];
            #pragma unroll
            for (int e = 0; e < 4; ++e) {
                if (k == 3 && e == 3) continue;   // j = 15 doesn't exist
                const int j = k * 4 + e;
                float w  = F4E(cw4, e);
                float wx = F4E(cx4, e);
                float wy = F4E(cy4, e);
                float u;
                u = fmaf(w, X0[j], -wx); a0 = fmaf(X0[j], u, a0);
                u = fmaf(w, Y0[j], -wy); a0 = fmaf(Y0[j], u, a0);
                u = fmaf(w, X1[j], -wx); a1 = fmaf(X1[j], u, a1);
                u = fmaf(w, Y1[j], -wy); a1 = fmaf(Y1[j], u, a1);
            }
        }
        // ascending within wave -> strict < keeps earliest q
        if (a0 < bv0) { bv0 = a0; bq0 = q; }
        if (a1 < bv1) { bv1 = a1; bq1 = q; }
    }
    bvred[wv][0][lane] = bv0;  bqred[wv][0][lane] = bq0;
    bvred[wv][1][lane] = bv1;  bqred[wv][1][lane] = bq1;
    __syncthreads();

    // ---- waves 0,1 finish person 0,1: combine by (value, q) + epilogue ----
#define EPILOGUE(PI, XA, YA)                                                  \
    if (wv == PI) {                                                           \
        float bestv = bvred[0][PI][lane];                                     \
        int   bestq = bqred[0][PI][lane];                                     \
        _Pragma("unroll")                                                     \
        for (int k = 1; k < 4; ++k) {                                         \
            float v  = bvred[k][PI][lane];                                    \
            int   qq = bqred[k][PI][lane];                                    \
            if (v < bestv || (v == bestv && qq < bestq)) {                    \
                bestv = v; bestq = qq;                                        \
            }                                                                 \
        }                                                                     \
        const int obase = ((b * NPERS + p0 + PI) * NJOINT) * NDEPTH + d;      \
        _Pragma("unroll")                                                     \
        for (int j = 0; j < NJOINT; ++j) {                                    \
            float4 v = sq[bestq][j];                                          \
            float xx = XA[j], yy = YA[j];                                     \
            float dx = xx - v.y;                                              \
            float dy = yy - v.z;                                              \
            float md = fmaf(dx, dx, dy * dy);                                 \
            float sc = __expf(-md * (1.0f / 225.0f));                         \
            float inb = (xx >= 0.0f && yy >= 0.0f &&                          \
                         xx <= iwm1 && yy <= ihm1) ? 1.0f : 0.0f;             \
            out[obase + j * NDEPTH] = sc * inb * v.x;                         \
        }                                                                     \
    }

    EPILOGUE(0, X0, Y0)
    EPILOGUE(1, X1, Y1)
#undef EPILOGUE
}

extern "C" void kernel_launch(void* const* d_in, const int* in_sizes, int n_in,
                              void* d_out, int out_size, void* d_ws, size_t ws_size,
                              hipStream_t stream) {
    const float* poses_3d = (const float*)d_in[0];
    const float* p2d      = (const float*)d_in[1];
    const float* vis      = (const float*)d_in[2];
    const int*   nper     = (const int*)d_in[3];
    const float* Rm       = (const float*)d_in[4];
    const float* Tm       = (const float*)d_in[5];
    const float* fm       = (const float*)d_in[6];
    const float* cm       = (const float*)d_in[7];
    const float* iw       = (const float*)d_in[8];
    const float* ih       = (const float*)d_in[9];
    float* out = (float*)d_out;

    const int B = in_sizes[3];  // num_persons_ref has B elements
    dim3 grid(B * 64);          // (b, person-pair, depth-half)
    dim3 block(256);            // 4 waves = 4 strided q-slices
    pose_match_kernel<<<grid, block, 0, stream>>>(
        poses_3d, p2d, vis, nper, Rm, Tm, fm, cm, iw, ih, out);
}